// Round 3
// baseline (87.270 us; speedup 1.0000x reference)
//
#include <hip/hip_runtime.h>

#define NHEADS 64
#define INF    128
#define OUTF   128
#define SPLITS 16     // grid = 64*16 = 1024 blocks = 4/CU -> 16 waves/CU
#define BLOCK  256
#define RROWS  8      // rows per batch per wave
#define WMASKS 2      // wave scans 128 rows (2 ballots), expected 2 matches

// One fused kernel, no LDS, no atomics, no syncthreads.
// Block (h,s): 4 waves each ballot-scan a 128-row window of head_ix for head h.
// Matching rows (wave-uniform scalars) are processed 8 at a time:
//   - x via scalar loads (uniform address -> SGPR operand to FMA)
//   - W[h] rows via coalesced float2 global loads (L2-resident; default
//     round-robin dispatch pins head h to XCD h%8 -> 512 KB working set/XCD)
//   - lane owns outputs {2*lane, 2*lane+1}; 16 FMA per W-load.
__global__ __launch_bounds__(BLOCK) void fused_headgemv(
    const float* __restrict__ x, const float* __restrict__ W,
    const float* __restrict__ bias, const int* __restrict__ hix,
    float* __restrict__ out, int n) {
  const int h    = blockIdx.x;
  const int s    = blockIdx.y;
  const int lane = threadIdx.x & 63;
  const int w    = threadIdx.x >> 6;

  const int range = n / SPLITS;                   // 512 rows per block
  const int sub   = s * range + w * (range / 4);  // this wave's 128-row window

  unsigned long long mask[WMASKS];
#pragma unroll
  for (int c = 0; c < WMASKS; ++c) {
    int r  = sub + c * 64 + lane;
    int hv = (r < n) ? hix[r] : -1;
    mask[c] = __ballot(hv == h);
  }

  const float2  bv = ((const float2*)(bias + (size_t)h * OUTF))[lane];
  const float2* Wr = (const float2*)(W + (size_t)h * (INF * OUTF));

  int c = 0;
  unsigned long long m = mask[0];
  for (;;) {
    // ---- extract up to RROWS wave-uniform row indices ----
    int rows[RROWS];
    int nr = 0;
    while (nr < RROWS) {
      while (m == 0ull && c < WMASKS - 1) m = mask[++c];
      if (m == 0ull) break;
      int b = __ffsll(m) - 1;
      m &= m - 1;
      rows[nr++] = __builtin_amdgcn_readfirstlane(sub + c * 64 + b);
    }
    if (nr == 0) break;
#pragma unroll
    for (int r2 = 0; r2 < RROWS; ++r2)
      if (r2 >= nr) rows[r2] = rows[0];  // dup-pad; stores predicated

    const float* xr[RROWS];
#pragma unroll
    for (int r2 = 0; r2 < RROWS; ++r2) xr[r2] = x + (size_t)rows[r2] * INF;

    float2 acc[RROWS];
#pragma unroll
    for (int r2 = 0; r2 < RROWS; ++r2) acc[r2] = bv;

    for (int kc = 0; kc < INF; kc += 4) {
      float4 xc[RROWS];
#pragma unroll
      for (int r2 = 0; r2 < RROWS; ++r2)
        xc[r2] = *(const float4*)(xr[r2] + kc);  // uniform addr -> s_load
      float2 wv0 = Wr[(kc + 0) * 64 + lane];
      float2 wv1 = Wr[(kc + 1) * 64 + lane];
      float2 wv2 = Wr[(kc + 2) * 64 + lane];
      float2 wv3 = Wr[(kc + 3) * 64 + lane];
#pragma unroll
      for (int r2 = 0; r2 < RROWS; ++r2) {
        acc[r2].x = fmaf(xc[r2].x, wv0.x, acc[r2].x);
        acc[r2].y = fmaf(xc[r2].x, wv0.y, acc[r2].y);
        acc[r2].x = fmaf(xc[r2].y, wv1.x, acc[r2].x);
        acc[r2].y = fmaf(xc[r2].y, wv1.y, acc[r2].y);
        acc[r2].x = fmaf(xc[r2].z, wv2.x, acc[r2].x);
        acc[r2].y = fmaf(xc[r2].z, wv2.y, acc[r2].y);
        acc[r2].x = fmaf(xc[r2].w, wv3.x, acc[r2].x);
        acc[r2].y = fmaf(xc[r2].w, wv3.y, acc[r2].y);
      }
    }

#pragma unroll
    for (int r2 = 0; r2 < RROWS; ++r2)
      if (r2 < nr)
        ((float2*)(out + (size_t)rows[r2] * OUTF))[lane] = acc[r2];
  }
}

extern "C" void kernel_launch(void* const* d_in, const int* in_sizes, int n_in,
                              void* d_out, int out_size, void* d_ws, size_t ws_size,
                              hipStream_t stream) {
  const float* x    = (const float*)d_in[0];
  const float* W    = (const float*)d_in[1];
  const float* bias = (const float*)d_in[2];
  const int*   hix  = (const int*)d_in[3];
  float* out = (float*)d_out;

  const int n = in_sizes[3];  // 8192 rows

  dim3 grid(NHEADS, SPLITS);
  fused_headgemv<<<grid, BLOCK, 0, stream>>>(x, W, bias, hix, out, n);
}

// Round 4
// 86.042 us; speedup vs baseline: 1.0143x; 1.0143x over previous
//
#include <hip/hip_runtime.h>

#define NHEADS 64
#define INF    128
#define OUTF   128
#define GRIDY  16     // grid 64x16 = 1024 blocks = 4/CU; (h+64y)%8 == h%8 -> W[h] pinned to XCD h%8
#define BLOCK  256
#define RROWS  4      // matches Poisson(2) expectation of the 128-row window; P(X>4)=5%
#define WMASKS 2      // wave scans 128 rows (2 ballots)

// Single fused kernel: ballot-scan + batched GEMV.
// Wave (h, y, w) scans rows [ (y*4+w)*128, +128 ) for head h; matched rows
// (wave-uniform) are processed 4 at a time:
//   - x[row] k-chunks via uniform-address loads (scalar path, SGPR operand)
//   - W[h] rows as coalesced float2 loads from L2 (XCD-pinned working set)
//   - lane owns outputs {2*lane, 2*lane+1}: 8 FMA per W-load per chunk-row
__global__ __launch_bounds__(BLOCK) void fused_headgemv(
    const float* __restrict__ x, const float* __restrict__ W,
    const float* __restrict__ bias, const int* __restrict__ hix,
    float* __restrict__ out, int n) {
  const int h    = blockIdx.x;
  const int y    = blockIdx.y;
  const int lane = threadIdx.x & 63;
  const int w    = threadIdx.x >> 6;

  const int win = n / (GRIDY * 4);        // 128 rows per wave
  const int sub = (y * 4 + w) * win;

  unsigned long long mask[WMASKS];
#pragma unroll
  for (int c = 0; c < WMASKS; ++c) {
    int r  = sub + c * 64 + lane;
    int hv = (r < n) ? hix[r] : -1;
    mask[c] = __ballot(hv == h);
  }

  const float2  bv = ((const float2*)(bias + (size_t)h * OUTF))[lane];
  const float2* Wr = (const float2*)(W + (size_t)h * (INF * OUTF));

  int c = 0;
  unsigned long long m = mask[0];
  for (;;) {
    int rows[RROWS];
    int nr = 0;
    while (nr < RROWS) {
      while (m == 0ull && c < WMASKS - 1) m = mask[++c];
      if (m == 0ull) break;
      int b = __ffsll(m) - 1;
      m &= m - 1;
      rows[nr++] = __builtin_amdgcn_readfirstlane(sub + c * 64 + b);
    }
    if (nr == 0) break;
#pragma unroll
    for (int r2 = 0; r2 < RROWS; ++r2)
      if (r2 >= nr) rows[r2] = rows[0];        // dup-pad; stores predicated

    const float* xr[RROWS];
#pragma unroll
    for (int r2 = 0; r2 < RROWS; ++r2) xr[r2] = x + (size_t)rows[r2] * INF;

    float2 acc[RROWS];
#pragma unroll
    for (int r2 = 0; r2 < RROWS; ++r2) acc[r2] = bv;

#pragma unroll 4
    for (int kc = 0; kc < INF; kc += 8) {
      // 4 rows x 8 k-values, uniform addresses -> scalar loads
      float4 xa[RROWS], xb[RROWS];
#pragma unroll
      for (int r2 = 0; r2 < RROWS; ++r2) {
        xa[r2] = *(const float4*)(xr[r2] + kc);
        xb[r2] = *(const float4*)(xr[r2] + kc + 4);
      }
#pragma unroll
      for (int i = 0; i < 8; ++i) {
        float2 wv = Wr[(size_t)(kc + i) * 64 + lane];
        float xs0 = (i < 4) ? ((const float*)&xa[0])[i & 3] : ((const float*)&xb[0])[i & 3];
        float xs1 = (i < 4) ? ((const float*)&xa[1])[i & 3] : ((const float*)&xb[1])[i & 3];
        float xs2 = (i < 4) ? ((const float*)&xa[2])[i & 3] : ((const float*)&xb[2])[i & 3];
        float xs3 = (i < 4) ? ((const float*)&xa[3])[i & 3] : ((const float*)&xb[3])[i & 3];
        acc[0].x = fmaf(xs0, wv.x, acc[0].x); acc[0].y = fmaf(xs0, wv.y, acc[0].y);
        acc[1].x = fmaf(xs1, wv.x, acc[1].x); acc[1].y = fmaf(xs1, wv.y, acc[1].y);
        acc[2].x = fmaf(xs2, wv.x, acc[2].x); acc[2].y = fmaf(xs2, wv.y, acc[2].y);
        acc[3].x = fmaf(xs3, wv.x, acc[3].x); acc[3].y = fmaf(xs3, wv.y, acc[3].y);
      }
    }

#pragma unroll
    for (int r2 = 0; r2 < RROWS; ++r2)
      if (r2 < nr)
        ((float2*)(out + (size_t)rows[r2] * OUTF))[lane] = acc[r2];
  }
}

extern "C" void kernel_launch(void* const* d_in, const int* in_sizes, int n_in,
                              void* d_out, int out_size, void* d_ws, size_t ws_size,
                              hipStream_t stream) {
  const float* x    = (const float*)d_in[0];
  const float* W    = (const float*)d_in[1];
  const float* bias = (const float*)d_in[2];
  const int*   hix  = (const int*)d_in[3];
  float* out = (float*)d_out;

  const int n = in_sizes[3];  // 8192 rows

  dim3 grid(NHEADS, GRIDY);
  fused_headgemv<<<grid, BLOCK, 0, stream>>>(x, W, bias, hix, out, n);
}

// Round 5
// 82.127 us; speedup vs baseline: 1.0626x; 1.0477x over previous
//
#include <hip/hip_runtime.h>

#define NHEADS 64
#define INF    128
#define OUTF   128
#define SPLITS 8      // grid 64x8 = 512 blocks = 2/CU (64 KB LDS-limited)
#define BLOCK  256
#define RROWS  4      // window 256 rows -> lambda=4 matches; dup-pad waste ~1.4x
#define WMASKS 4      // wave scans 256 rows (4 ballots)

// Fused single-dispatch kernel, R2 skeleton + upgrades:
//  - W[h] (64 KB) staged to LDS via global_load_lds width=16 (no VGPR trip)
//  - inner loop: 1 ds_read_b64 (lane owns outs {2l,2l+1}) + 8 FMA per k
//  - x rows are wave-uniform (readfirstlane'd) -> scalar-path float4 loads
__global__ __launch_bounds__(BLOCK) void fused_headgemv(
    const float* __restrict__ x, const float* __restrict__ W,
    const float* __restrict__ bias, const int* __restrict__ hix,
    float* __restrict__ out, int n) {
  __shared__ float Ws[INF * OUTF];  // 64 KB

  const int h    = blockIdx.x;
  const int s    = blockIdx.y;
  const int lane = threadIdx.x & 63;
  const int w    = threadIdx.x >> 6;

  // ---- stage W[h] -> LDS: 16 passes x (4 waves x 64 lanes x 16 B) ----
  {
    const char* Wg = (const char*)(W + (size_t)h * (INF * OUTF));
#pragma unroll
    for (int p = 0; p < 16; ++p) {
      int chunk = (p * 4 + w) * 64;  // in 16B units; wave-uniform
      __builtin_amdgcn_global_load_lds(
          (const __attribute__((address_space(1))) void*)(Wg + (size_t)(chunk + lane) * 16),
          (__attribute__((address_space(3))) void*)((char*)Ws + (size_t)chunk * 16),
          16, 0, 0);
    }
  }

  // ---- scan this wave's 256-row window while the DMA flies ----
  const int range = n / SPLITS;                   // 1024 rows per block
  const int sub   = s * range + w * (range / 4);  // wave's 256-row window
  unsigned long long mask[WMASKS];
#pragma unroll
  for (int c = 0; c < WMASKS; ++c) {
    int r  = sub + c * 64 + lane;
    int hv = (r < n) ? hix[r] : -1;
    mask[c] = __ballot(hv == h);
  }

  const float2 bv = ((const float2*)(bias + (size_t)h * OUTF))[lane];

  __builtin_amdgcn_s_waitcnt(0);  // drain global_load_lds before barrier
  __syncthreads();

  int c = 0;
  unsigned long long m = mask[0];
  for (;;) {
    // ---- extract up to RROWS wave-uniform row indices ----
    int rows[RROWS];
    int nr = 0;
    while (nr < RROWS) {
      while (m == 0ull && c < WMASKS - 1) m = mask[++c];
      if (m == 0ull) break;
      int b = __ffsll(m) - 1;
      m &= m - 1;
      rows[nr++] = __builtin_amdgcn_readfirstlane(sub + c * 64 + b);
    }
    if (nr == 0) break;
#pragma unroll
    for (int r2 = 0; r2 < RROWS; ++r2)
      if (r2 >= nr) rows[r2] = rows[0];  // dup-pad; stores predicated

    const float* xr[RROWS];
#pragma unroll
    for (int r2 = 0; r2 < RROWS; ++r2) xr[r2] = x + (size_t)rows[r2] * INF;

    float2 acc[RROWS];
#pragma unroll
    for (int r2 = 0; r2 < RROWS; ++r2) acc[r2] = bv;

#pragma unroll 2
    for (int kc = 0; kc < INF; kc += 8) {
      float4 xa[RROWS], xb[RROWS];
#pragma unroll
      for (int r2 = 0; r2 < RROWS; ++r2) {
        xa[r2] = *(const float4*)(xr[r2] + kc);      // uniform -> s_load
        xb[r2] = *(const float4*)(xr[r2] + kc + 4);
      }
#pragma unroll
      for (int i = 0; i < 8; ++i) {
        // lane owns outputs {2*lane, 2*lane+1}: one ds_read_b64 per k
        float2 wv = *(const float2*)&Ws[(kc + i) * OUTF + 2 * lane];
        float xs0 = (i < 4) ? ((const float*)&xa[0])[i & 3] : ((const float*)&xb[0])[i & 3];
        float xs1 = (i < 4) ? ((const float*)&xa[1])[i & 3] : ((const float*)&xb[1])[i & 3];
        float xs2 = (i < 4) ? ((const float*)&xa[2])[i & 3] : ((const float*)&xb[2])[i & 3];
        float xs3 = (i < 4) ? ((const float*)&xa[3])[i & 3] : ((const float*)&xb[3])[i & 3];
        acc[0].x = fmaf(xs0, wv.x, acc[0].x); acc[0].y = fmaf(xs0, wv.y, acc[0].y);
        acc[1].x = fmaf(xs1, wv.x, acc[1].x); acc[1].y = fmaf(xs1, wv.y, acc[1].y);
        acc[2].x = fmaf(xs2, wv.x, acc[2].x); acc[2].y = fmaf(xs2, wv.y, acc[2].y);
        acc[3].x = fmaf(xs3, wv.x, acc[3].x); acc[3].y = fmaf(xs3, wv.y, acc[3].y);
      }
    }

#pragma unroll
    for (int r2 = 0; r2 < RROWS; ++r2)
      if (r2 < nr)
        ((float2*)(out + (size_t)rows[r2] * OUTF))[lane] = acc[r2];
  }
}

extern "C" void kernel_launch(void* const* d_in, const int* in_sizes, int n_in,
                              void* d_out, int out_size, void* d_ws, size_t ws_size,
                              hipStream_t stream) {
  const float* x    = (const float*)d_in[0];
  const float* W    = (const float*)d_in[1];
  const float* bias = (const float*)d_in[2];
  const int*   hix  = (const int*)d_in[3];
  float* out = (float*)d_out;

  const int n = in_sizes[3];  // 8192 rows

  dim3 grid(NHEADS, SPLITS);
  fused_headgemv<<<grid, BLOCK, 0, stream>>>(x, W, bias, hix, out, n);
}